// Round 7
// baseline (1182.750 us; speedup 1.0000x reference)
//
#include <hip/hip_runtime.h>
#include <math.h>

// TrfEdgeNetRand: 3x TransformerConv(heads=1) + ReLU + classifier on MI355X.
// R7:
//  - k_gemm: M=64 per block (wave = 4 row-frags x 4 col-tiles, acc[4][4]),
//    cuts B L2-re-read traffic ~4GB -> ~1.1GB
//  - classifier fused into layer-3 k_edge epilogue (h3 never materialized)
//  - eattr permuted to CSR order as bf16 (eperm) in k_fill: streaming attr
//    reads; srcid shrinks to int
//  - k_edge: srcid+attr prefetch (next pair only; NOT R5's k/v pipeline)
//  - launches 24 -> 19 (merged zero, merged packw+bias, dropped k_cls)

typedef unsigned int uint;
typedef unsigned short ushort;
typedef __bf16 bf16x8 __attribute__((ext_vector_type(8)));
typedef float f32x4 __attribute__((ext_vector_type(4)));

__device__ __forceinline__ ushort f2bf(float f) {
    uint u = __float_as_uint(f);
    u += 0x7fffu + ((u >> 16) & 1u);   // round-to-nearest-even
    return (ushort)(u >> 16);
}
__device__ __forceinline__ float bf2f(ushort h) {
    return __uint_as_float(((uint)h) << 16);
}
__device__ __forceinline__ void unpack8(uint4 t, float* o) {
    o[0] = bf2f((ushort)(t.x & 0xffffu)); o[1] = bf2f((ushort)(t.x >> 16));
    o[2] = bf2f((ushort)(t.y & 0xffffu)); o[3] = bf2f((ushort)(t.y >> 16));
    o[4] = bf2f((ushort)(t.z & 0xffffu)); o[5] = bf2f((ushort)(t.z >> 16));
    o[6] = bf2f((ushort)(t.w & 0xffffu)); o[7] = bf2f((ushort)(t.w >> 16));
}

// ---------------- utility kernels ----------------
__global__ void k_zero(uint* p, int n) {
    int i = blockIdx.x * 256 + threadIdx.x;
    if (i < n) p[i] = 0u;
}

__global__ void k_hist(const int* __restrict__ dst, uint* __restrict__ counts, int E, int N) {
    int e = blockIdx.x * 256 + threadIdx.x;
    if (e < E) {
        int d = dst[e];
        d = (d < 0) ? 0 : (d >= N ? N - 1 : d);
        atomicAdd(&counts[d], 1u);
    }
}

__global__ void k_scan1(const uint* __restrict__ counts, uint* __restrict__ bsum, int n) {
    __shared__ uint sm[256];
    int tid = threadIdx.x;
    int base = blockIdx.x * 1024 + tid * 4;
    uint s = 0;
#pragma unroll
    for (int j = 0; j < 4; ++j)
        if (base + j < n) s += counts[base + j];
    sm[tid] = s;
    __syncthreads();
    for (int d = 128; d > 0; d >>= 1) {
        if (tid < d) sm[tid] += sm[tid + d];
        __syncthreads();
    }
    if (tid == 0) bsum[blockIdx.x] = sm[0];
}

__global__ void k_scan2(uint* bsum, int nb) {
    if (threadIdx.x == 0 && blockIdx.x == 0) {
        uint run = 0;
        for (int i = 0; i < nb; ++i) { uint v = bsum[i]; bsum[i] = run; run += v; }
    }
}

__global__ void k_scan3(const uint* __restrict__ counts, const uint* __restrict__ bsum,
                        uint* __restrict__ row_ptr, int n, int E) {
    __shared__ uint sm[256];
    int tid = threadIdx.x;
    int base = blockIdx.x * 1024 + tid * 4;
    uint local[4];
    uint s = 0;
#pragma unroll
    for (int j = 0; j < 4; ++j) {
        local[j] = (base + j < n) ? counts[base + j] : 0u;
        s += local[j];
    }
    sm[tid] = s;
    __syncthreads();
    for (int d = 1; d < 256; d <<= 1) {
        uint v = (tid >= d) ? sm[tid - d] : 0u;
        __syncthreads();
        sm[tid] += v;
        __syncthreads();
    }
    uint run = sm[tid] - s + bsum[blockIdx.x];
#pragma unroll
    for (int j = 0; j < 4; ++j)
        if (base + j < n) { row_ptr[base + j] = run; run += local[j]; }
    if (blockIdx.x == 0 && tid == 0) row_ptr[n] = (uint)E;
}

// CSR fill: srci (src only) + eattr permuted to CSR order as bf16
__global__ void k_fill(const int* __restrict__ ei, const float* __restrict__ eattr,
                       const uint* __restrict__ row_ptr, uint* __restrict__ cursor,
                       int* __restrict__ srci, ushort* __restrict__ eperm, int E, int N) {
    int e = blockIdx.x * 256 + threadIdx.x;
    if (e >= E) return;
    int s = ei[e];
    int d = ei[E + e];
    s = (s < 0) ? 0 : (s >= N ? N - 1 : s);
    d = (d < 0) ? 0 : (d >= N ? N - 1 : d);
    uint idx = row_ptr[d] + atomicAdd(&cursor[d], 1u);
    srci[idx] = s;
    const float4* sv = (const float4*)(eattr + (size_t)e * 16);
    float4 a0 = sv[0], a1 = sv[1], a2 = sv[2], a3 = sv[3];
    uint4 o0, o1;
    o0.x = (uint)f2bf(a0.x) | ((uint)f2bf(a0.y) << 16);
    o0.y = (uint)f2bf(a0.z) | ((uint)f2bf(a0.w) << 16);
    o0.z = (uint)f2bf(a1.x) | ((uint)f2bf(a1.y) << 16);
    o0.w = (uint)f2bf(a1.z) | ((uint)f2bf(a1.w) << 16);
    o1.x = (uint)f2bf(a2.x) | ((uint)f2bf(a2.y) << 16);
    o1.y = (uint)f2bf(a2.z) | ((uint)f2bf(a2.w) << 16);
    o1.z = (uint)f2bf(a3.x) | ((uint)f2bf(a3.y) << 16);
    o1.w = (uint)f2bf(a3.z) | ((uint)f2bf(a3.w) << 16);
    *(uint4*)(eperm + (size_t)idx * 16) = o0;
    *(uint4*)(eperm + (size_t)idx * 16 + 8) = o1;
}

__global__ void k_cvt(const float4* __restrict__ in, ushort4* __restrict__ outp, int n4) {
    int i = blockIdx.x * 256 + threadIdx.x;
    if (i >= n4) return;
    float4 v = in[i];
    ushort4 o;
    o.x = f2bf(v.x); o.y = f2bf(v.y); o.z = f2bf(v.z); o.w = f2bf(v.w);
    outp[i] = o;
}

// ---------------- g-projection pre-pack: Wgf[k][f] = sum_c Wq[k,c]*We[f,c] ----
__global__ void k_packg(const float* __restrict__ Wq, const float* __restrict__ bq,
                        const float* __restrict__ We, float* __restrict__ Wgf,
                        float* __restrict__ bgf, int C) {
    int id = blockIdx.x * 256 + threadIdx.x;
    if (id < 2048) {
        int k = id >> 4, f = id & 15;
        float s = 0.f;
        for (int c = 0; c < C; ++c) s = fmaf(Wq[k * C + c], We[f * C + c], s);
        Wgf[id] = s;              // layout [k*16+f]
    } else if (id < 2064) {
        int f = id - 2048;
        float s = 0.f;
        for (int c = 0; c < C; ++c) s = fmaf(bq[c], We[f * C + c], s);
        bgf[f] = s;
    }
}

// ---------- weight pack (cols: Wq|Wk|Wv|Ws|Wg -> 4C+16) + bias, merged -------
__global__ void k_packwb(const float* __restrict__ Wq, const float* __restrict__ bq,
                         const float* __restrict__ Wk, const float* __restrict__ bk,
                         const float* __restrict__ Wv, const float* __restrict__ bv,
                         const float* __restrict__ Ws, const float* __restrict__ bs,
                         const float* __restrict__ Wgf, const float* __restrict__ bgf,
                         ushort* __restrict__ Bp, float* __restrict__ biasc, int C) {
    int P = 4 * C + 16;
    int nct = P >> 4;
    int total = 4 * nct * 512;
    int id = blockIdx.x * 256 + threadIdx.x;
    if (id < total) {
        int j = id & 7;
        int rest = id >> 3;
        int lane = rest & 63;
        rest >>= 6;
        int ct = rest % nct;
        int kt = rest / nct;
        int k = kt * 32 + ((lane >> 4) << 3) + j;
        int c = (ct << 4) + (lane & 15);
        float w;
        if (c < 4 * C) {
            int mat = c / C, cc = c % C;
            const float* W = (mat == 0) ? Wq : (mat == 1) ? Wk : (mat == 2) ? Wv : Ws;
            w = W[k * C + cc];
        } else {
            w = Wgf[k * 16 + (c - 4 * C)];
        }
        Bp[id] = f2bf(w);
    } else if (id < total + P) {
        int c = id - total;
        float v;
        if (c < 4 * C) {
            int mat = c / C, cc = c % C;
            const float* b = (mat == 0) ? bq : (mat == 1) ? bk : (mat == 2) ? bv : bs;
            v = b[cc];
        } else {
            v = bgf[c - 4 * C];
        }
        biasc[c] = v;
    }
}

// ---------------- fused QKVSG GEMM (bf16 MFMA), 64-row x 256-col blocks ------
// A: [N,128] bf16. Cols [0,3C)->H (q|k|v), [3C,4C)->S (skip), [4C,4C+16)->g.
// Block = 4 waves (col-slices of 64); each wave: 4 row-frags x 4 col-tiles.
__global__ __launch_bounds__(256) void k_gemm(const ushort* __restrict__ A,
                                              const ushort* __restrict__ Bp,
                                              const float* __restrict__ bias,
                                              ushort* __restrict__ H,
                                              ushort* __restrict__ S,
                                              ushort* __restrict__ g, int C, int N) {
    int fourC = 4 * C, threeC = 3 * C;
    int P = fourC + 16;
    int nct = P >> 4;
    int lane = threadIdx.x & 63;
    int wave = threadIdx.x >> 6;
    int quad = lane >> 4;
    int r = lane & 15;
    int m0 = blockIdx.y << 6;                       // 64 rows per block
    int ct0 = (blockIdx.x << 4) + (wave << 2);      // 4 col-tiles per wave
    if (ct0 >= nct) return;

    f32x4 acc[4][4];
#pragma unroll
    for (int rt = 0; rt < 4; ++rt)
#pragma unroll
        for (int i = 0; i < 4; ++i) acc[rt][i] = (f32x4){0.f, 0.f, 0.f, 0.f};

#pragma unroll
    for (int kk = 0; kk < 4; ++kk) {
        bf16x8 a[4];
#pragma unroll
        for (int rt = 0; rt < 4; ++rt) {
            int row = m0 + rt * 16 + r;
            if (row >= N) row = N - 1;              // pad rows: garbage, masked at store
            a[rt] = *(const bf16x8*)(A + (size_t)row * 128 + kk * 32 + (quad << 3));
        }
#pragma unroll
        for (int i = 0; i < 4; ++i) {
            if (ct0 + i < nct) {
                bf16x8 b = *(const bf16x8*)(Bp + ((size_t)((kk * nct + ct0 + i) << 6) + lane) * 8);
#pragma unroll
                for (int rt = 0; rt < 4; ++rt)
                    acc[rt][i] = __builtin_amdgcn_mfma_f32_16x16x32_bf16(a[rt], b, acc[rt][i], 0, 0, 0);
            }
        }
    }
#pragma unroll
    for (int i = 0; i < 4; ++i) {
        int cc = ((ct0 + i) << 4) + r;
        if (cc >= P) continue;
        float bi = bias[cc];
#pragma unroll
        for (int rt = 0; rt < 4; ++rt) {
#pragma unroll
            for (int reg = 0; reg < 4; ++reg) {
                int rr = m0 + rt * 16 + (quad << 2) + reg;
                if (rr >= N) continue;
                ushort val = f2bf(acc[rt][i][reg] + bi);
                if (cc < threeC)      H[(size_t)rr * threeC + cc] = val;
                else if (cc < fourC)  S[(size_t)rr * C + (cc - threeC)] = val;
                else                  g[(size_t)rr * 16 + (cc - fourC)] = val;
            }
        }
    }
}

// ---------------- edge attention: GSIZE-lane group per node, plain exp -------
// H: [N,3C] bf16 (q|k|v). S: skip on entry; output written to S (FUSECLS=false)
// or directly to the classifier output d_out (FUSECLS=true, C=256).
// Logits |alpha|<~2 by construction (W~N(0,0.05^2)) -> plain exp == softmax.
template <int C, int GSIZE, bool RELU, bool FUSECLS>
__global__ __launch_bounds__(256, 6) void k_edge(const ushort* __restrict__ H,
                                                 ushort* __restrict__ S,
                                                 const ushort* __restrict__ g,
                                                 const uint* __restrict__ row_ptr,
                                                 const int* __restrict__ srci,
                                                 const ushort* __restrict__ eperm,
                                                 const float* __restrict__ We,
                                                 const float* __restrict__ Wc,
                                                 const float* __restrict__ bc,
                                                 float* __restrict__ outp,
                                                 int N) {
    constexpr int VR = C / GSIZE;        // 8
    constexpr int TH = 3 * C;
    constexpr int GPB = 256 / GSIZE;     // groups per block
    __shared__ float swex[GPB][17];      // +1 pad: conflict-free group reads
    const float scale = (C == 128) ? 0.08838834764831843f : 0.0625f;  // 1/sqrt(C)
    const float foldk = 16.0f / (float)GSIZE;  // attr replication compensation

    int lane = threadIdx.x & (GSIZE - 1);
    int grp = threadIdx.x / GSIZE;
    int f = lane & 15;
    int node = blockIdx.x * GPB + grp;
    if (node >= N) return;

    float q[VR];
    {
        uint4 tt = *(const uint4*)(H + (size_t)node * TH + lane * VR);
        unpack8(tt, q);
    }
    float gl = bf2f(g[(size_t)node * 16 + f]);
    uint beg = row_ptr[node], end = row_ptr[node + 1];

    float l = 0.f, w = 0.f;
    float acc[VR];
#pragma unroll
    for (int j = 0; j < VR; ++j) acc[j] = 0.f;

    if (beg < end) {
        bool h1 = (beg + 1 < end);
        int s0 = srci[beg];
        int s1 = h1 ? srci[beg + 1] : s0;
        float a0 = bf2f(eperm[(size_t)beg * 16 + f]);
        float a1 = h1 ? bf2f(eperm[(size_t)(beg + 1) * 16 + f]) : 0.f;
        for (uint t = beg; t < end; t += 2) {
            // issue k/v gathers for current pair (addresses ready from prefetch)
            uint4 k0 = *(const uint4*)(H + (size_t)s0 * TH + C + lane * VR);
            uint4 v0 = *(const uint4*)(H + (size_t)s0 * TH + 2 * C + lane * VR);
            uint4 k1, v1;
            if (h1) {
                k1 = *(const uint4*)(H + (size_t)s1 * TH + C + lane * VR);
                v1 = *(const uint4*)(H + (size_t)s1 * TH + 2 * C + lane * VR);
            }
            // prefetch next pair's src + attr while gathers are in flight
            uint tn = t + 2;
            bool h0n = (tn < end);
            bool h1n = (tn + 1 < end);
            int s0n = s0, s1n;
            float a0n = 0.f, a1n = 0.f;
            if (h0n) { s0n = srci[tn]; a0n = bf2f(eperm[(size_t)tn * 16 + f]); }
            s1n = h1n ? srci[tn + 1] : s0n;
            if (h1n) a1n = bf2f(eperm[(size_t)(tn + 1) * 16 + f]);
            // compute pair
            float kf[VR];
            unpack8(k0, kf);
            float p0 = foldk * a0 * gl;               // attr.g folded into reduce
#pragma unroll
            for (int j = 0; j < VR; ++j) p0 = fmaf(q[j], kf[j], p0);
            float p1 = 0.f;
            if (h1) {
                unpack8(k1, kf);
                p1 = foldk * a1 * gl;
#pragma unroll
                for (int j = 0; j < VR; ++j) p1 = fmaf(q[j], kf[j], p1);
            }
            p0 += __shfl_xor(p0, 1); p1 += __shfl_xor(p1, 1);
            p0 += __shfl_xor(p0, 2); p1 += __shfl_xor(p1, 2);
            p0 += __shfl_xor(p0, 4); p1 += __shfl_xor(p1, 4);
            p0 += __shfl_xor(p0, 8); p1 += __shfl_xor(p1, 8);
            if (GSIZE == 32) { p0 += __shfl_xor(p0, 16); p1 += __shfl_xor(p1, 16); }
            float e0 = __expf(p0 * scale);
            float e1 = h1 ? __expf(p1 * scale) : 0.f;
            l += e0 + e1;
            w = fmaf(e0, a0, w);
            w = fmaf(e1, a1, w);
            float vf[VR];
            unpack8(v0, vf);
#pragma unroll
            for (int j = 0; j < VR; ++j) acc[j] = fmaf(e0, vf[j], acc[j]);
            if (h1) {
                unpack8(v1, vf);
#pragma unroll
                for (int j = 0; j < VR; ++j) acc[j] = fmaf(e1, vf[j], acc[j]);
            }
            s0 = s0n; s1 = s1n; a0 = a0n; a1 = a1n; h1 = h1n;
        }
    }

    float inv = 1.f / (l + 1e-16f);   // empty node: acc=w=0 -> out = skip
    // exchange w_f (held on lane f; duplicated on lane 16+f when GSIZE=32)
    if (lane < 16) swex[grp][lane] = w;
    // same-wave LDS RAW: compiler inserts lgkmcnt wait; no barrier needed
    float ew[VR];
#pragma unroll
    for (int j = 0; j < VR; ++j) ew[j] = 0.f;
#pragma unroll
    for (int f2 = 0; f2 < 16; ++f2) {
        float wf = swex[grp][f2];
        const float* wrow = We + f2 * C + lane * VR;
#pragma unroll
        for (int u = 0; u < VR / 4; ++u) {
            float4 cv = *(const float4*)(wrow + u * 4);
            ew[u * 4 + 0] = fmaf(wf, cv.x, ew[u * 4 + 0]);
            ew[u * 4 + 1] = fmaf(wf, cv.y, ew[u * 4 + 1]);
            ew[u * 4 + 2] = fmaf(wf, cv.z, ew[u * 4 + 2]);
            ew[u * 4 + 3] = fmaf(wf, cv.w, ew[u * 4 + 3]);
        }
    }
    const ushort* srow = S + (size_t)node * C + lane * VR;
    uint4 skv = *(const uint4*)srow;
    float sk[8];
    unpack8(skv, sk);
    float o[8];
#pragma unroll
    for (int j = 0; j < VR; ++j) {
        o[j] = (acc[j] + ew[j]) * inv + sk[j];
        if (RELU) o[j] = fmaxf(o[j], 0.f);
    }
    if (!FUSECLS) {
        uint4 ov;
        uint* op = (uint*)&ov;
#pragma unroll
        for (int h = 0; h < 4; ++h)
            op[h] = (uint)f2bf(o[2 * h]) | ((uint)f2bf(o[2 * h + 1]) << 16);
        *(uint4*)(S + (size_t)node * C + lane * VR) = ov;
    } else {
        // classifier: logits[c] = sum_j h3[j] * Wc[j][c] + bc[c]; h3 row split
        // across GSIZE lanes (lane holds cols lane*VR..+VR-1). bf16-round h3
        // first to match the non-fused numerics of previous rounds.
        float logit[10];
#pragma unroll
        for (int c = 0; c < 10; ++c) logit[c] = 0.f;
        const float* wcr = Wc + (size_t)(lane * VR) * 10;
#pragma unroll
        for (int j = 0; j < VR; ++j) {
            float hv = bf2f(f2bf(o[j]));
#pragma unroll
            for (int c = 0; c < 10; ++c) logit[c] = fmaf(hv, wcr[j * 10 + c], logit[c]);
        }
#pragma unroll
        for (int off = 1; off < GSIZE; off <<= 1)
#pragma unroll
            for (int c = 0; c < 10; ++c) logit[c] += __shfl_xor(logit[c], off);
        if (lane < 10) {
            float r = 0.f;
#pragma unroll
            for (int c = 0; c < 10; ++c) r = (lane == c) ? logit[c] : r;
            outp[(size_t)node * 10 + lane] = r + bc[lane];
        }
    }
}

// ---------------- launch ----------------
extern "C" void kernel_launch(void* const* d_in, const int* in_sizes, int n_in,
                              void* d_out, int out_size, void* d_ws, size_t ws_size,
                              hipStream_t stream) {
    const float* x = (const float*)d_in[0];
    const int* ei = (const int*)d_in[1];
    const float* eattr = (const float*)d_in[2];
    const int N = in_sizes[0] / 128;
    const int E = in_sizes[1] / 2;

    const float* Wq[3], *bq[3], *Wk[3], *bk[3], *Wv[3], *bv[3], *We[3], *Ws[3], *bs[3];
    for (int li = 0; li < 3; ++li) {
        int base = 3 + li * 9;
        Wq[li] = (const float*)d_in[base + 0];
        bq[li] = (const float*)d_in[base + 1];
        Wk[li] = (const float*)d_in[base + 2];
        bk[li] = (const float*)d_in[base + 3];
        Wv[li] = (const float*)d_in[base + 4];
        bv[li] = (const float*)d_in[base + 5];
        We[li] = (const float*)d_in[base + 6];
        Ws[li] = (const float*)d_in[base + 7];
        bs[li] = (const float*)d_in[base + 8];
    }
    const float* Wc = (const float*)d_in[30];
    const float* bc = (const float*)d_in[31];

    // workspace carve (~265 MB)
    size_t off = 0;
    char* base = (char*)d_ws;
    auto alloc = [&](size_t bytes) -> void* {
        void* p = base + off;
        off = (off + bytes + 255) & ~(size_t)255;
        return p;
    };
    ushort* SA = (ushort*)alloc((size_t)N * 256 * 2);   // skip/out ping
    ushort* SB = (ushort*)alloc((size_t)N * 128 * 2);   // pong (also xb)
    ushort* H  = (ushort*)alloc((size_t)N * 768 * 2);   // q|k|v (max 3C)
    ushort* gbuf = (ushort*)alloc((size_t)N * 16 * 2);  // g = We.q per node
    ushort* Bp = (ushort*)alloc(140000 * 2);            // packed weights
    float* biasc = (float*)alloc(1040 * 4);
    float* Wgf = (float*)alloc(2048 * 4);
    float* bgf = (float*)alloc(16 * 4);
    uint* row_ptr = (uint*)alloc((size_t)(N + 1) * 4);
    uint* counts = (uint*)alloc((size_t)N * 2 * 4);     // counts | cursor (adjacent)
    uint* cursor = counts + N;
    uint* bsum = (uint*)alloc(1024 * 4);
    int* srci = (int*)alloc((size_t)E * 4);
    ushort* eperm = (ushort*)alloc((size_t)E * 16 * 2); // bf16 attr in CSR order

    ushort* xb = SB;   // alias: xb dead after layer-1 GEMM

    int nb = (N + 1023) / 1024;

    // CSR build
    k_zero<<<(2 * N + 255) / 256, 256, 0, stream>>>(counts, 2 * N);
    k_hist<<<(E + 255) / 256, 256, 0, stream>>>(ei + E, counts, E, N);
    k_scan1<<<nb, 256, 0, stream>>>(counts, bsum, N);
    k_scan2<<<1, 64, 0, stream>>>(bsum, nb);
    k_scan3<<<nb, 256, 0, stream>>>(counts, bsum, row_ptr, N, E);
    k_fill<<<(E + 255) / 256, 256, 0, stream>>>(ei, eattr, row_ptr, cursor, srci, eperm, E, N);

    // x -> bf16
    int n4 = N * 128 / 4;
    k_cvt<<<(n4 + 255) / 256, 256, 0, stream>>>((const float4*)x, (ushort4*)xb, n4);

    int gy = (N + 63) / 64;   // GEMM 64-row blocks

    for (int li = 0; li < 3; ++li) {
        int C = (li == 2) ? 256 : 128;
        int P = 4 * C + 16;
        int nct = P >> 4;
        int packTotal = 4 * nct * 512 + P;
        const ushort* A = (li == 0) ? xb : (li == 1) ? SA : SB;
        ushort* Sout = (li == 1) ? SB : SA;

        k_packg<<<9, 256, 0, stream>>>(Wq[li], bq[li], We[li], Wgf, bgf, C);
        k_packwb<<<(packTotal + 255) / 256, 256, 0, stream>>>(
            Wq[li], bq[li], Wk[li], bk[li], Wv[li], bv[li], Ws[li], bs[li],
            Wgf, bgf, Bp, biasc, C);
        k_gemm<<<dim3((nct + 15) / 16, gy), 256, 0, stream>>>(A, Bp, biasc, H, Sout, gbuf, C, N);
        if (li == 2)
            k_edge<256, 32, false, true><<<(N * 32 + 255) / 256, 256, 0, stream>>>(
                H, Sout, gbuf, row_ptr, srci, eperm, We[li], Wc, bc, (float*)d_out, N);
        else
            k_edge<128, 16, true, false><<<(N * 16 + 255) / 256, 256, 0, stream>>>(
                H, Sout, gbuf, row_ptr, srci, eperm, We[li], nullptr, nullptr, nullptr, N);
    }
}

// Round 8
// 1131.989 us; speedup vs baseline: 1.0448x; 1.0448x over previous
//
#include <hip/hip_runtime.h>
#include <math.h>

// TrfEdgeNetRand: 3x TransformerConv(heads=1) + ReLU + classifier on MI355X.
// R8: A/B discipline round.
//  - k_edge: VERBATIM R6 structure (batch-2, no prefetch, int2 srcid, fp32
//    eattr random reads, plain exp, LDS w-exchange, separate k_cls) — the
//    config that measured 165us/494MB/50MB.
//  - keep R7 wins: M=64 GEMM (4 row-frags x 4 col-tiles), merged packw+bias,
//    merged zero; these cut non-edge time 526->297us.
//  - R7's k_edge restructure (prefetch + eperm + fused cls) regressed
//    165->295us with +364MB/dispatch HBM traffic — fully reverted.

typedef unsigned int uint;
typedef unsigned short ushort;
typedef __bf16 bf16x8 __attribute__((ext_vector_type(8)));
typedef float f32x4 __attribute__((ext_vector_type(4)));

__device__ __forceinline__ ushort f2bf(float f) {
    uint u = __float_as_uint(f);
    u += 0x7fffu + ((u >> 16) & 1u);   // round-to-nearest-even
    return (ushort)(u >> 16);
}
__device__ __forceinline__ float bf2f(ushort h) {
    return __uint_as_float(((uint)h) << 16);
}
__device__ __forceinline__ void unpack8(uint4 t, float* o) {
    o[0] = bf2f((ushort)(t.x & 0xffffu)); o[1] = bf2f((ushort)(t.x >> 16));
    o[2] = bf2f((ushort)(t.y & 0xffffu)); o[3] = bf2f((ushort)(t.y >> 16));
    o[4] = bf2f((ushort)(t.z & 0xffffu)); o[5] = bf2f((ushort)(t.z >> 16));
    o[6] = bf2f((ushort)(t.w & 0xffffu)); o[7] = bf2f((ushort)(t.w >> 16));
}

// ---------------- utility kernels ----------------
__global__ void k_zero(uint* p, int n) {
    int i = blockIdx.x * 256 + threadIdx.x;
    if (i < n) p[i] = 0u;
}

__global__ void k_hist(const int* __restrict__ dst, uint* __restrict__ counts, int E, int N) {
    int e = blockIdx.x * 256 + threadIdx.x;
    if (e < E) {
        int d = dst[e];
        d = (d < 0) ? 0 : (d >= N ? N - 1 : d);
        atomicAdd(&counts[d], 1u);
    }
}

__global__ void k_scan1(const uint* __restrict__ counts, uint* __restrict__ bsum, int n) {
    __shared__ uint sm[256];
    int tid = threadIdx.x;
    int base = blockIdx.x * 1024 + tid * 4;
    uint s = 0;
#pragma unroll
    for (int j = 0; j < 4; ++j)
        if (base + j < n) s += counts[base + j];
    sm[tid] = s;
    __syncthreads();
    for (int d = 128; d > 0; d >>= 1) {
        if (tid < d) sm[tid] += sm[tid + d];
        __syncthreads();
    }
    if (tid == 0) bsum[blockIdx.x] = sm[0];
}

__global__ void k_scan2(uint* bsum, int nb) {
    if (threadIdx.x == 0 && blockIdx.x == 0) {
        uint run = 0;
        for (int i = 0; i < nb; ++i) { uint v = bsum[i]; bsum[i] = run; run += v; }
    }
}

__global__ void k_scan3(const uint* __restrict__ counts, const uint* __restrict__ bsum,
                        uint* __restrict__ row_ptr, int n, int E) {
    __shared__ uint sm[256];
    int tid = threadIdx.x;
    int base = blockIdx.x * 1024 + tid * 4;
    uint local[4];
    uint s = 0;
#pragma unroll
    for (int j = 0; j < 4; ++j) {
        local[j] = (base + j < n) ? counts[base + j] : 0u;
        s += local[j];
    }
    sm[tid] = s;
    __syncthreads();
    for (int d = 1; d < 256; d <<= 1) {
        uint v = (tid >= d) ? sm[tid - d] : 0u;
        __syncthreads();
        sm[tid] += v;
        __syncthreads();
    }
    uint run = sm[tid] - s + bsum[blockIdx.x];
#pragma unroll
    for (int j = 0; j < 4; ++j)
        if (base + j < n) { row_ptr[base + j] = run; run += local[j]; }
    if (blockIdx.x == 0 && tid == 0) row_ptr[n] = (uint)E;
}

__global__ void k_fill(const int* __restrict__ ei, const uint* __restrict__ row_ptr,
                       uint* __restrict__ cursor, int2* __restrict__ srcid, int E, int N) {
    int e = blockIdx.x * 256 + threadIdx.x;
    if (e >= E) return;
    int s = ei[e];
    int d = ei[E + e];
    s = (s < 0) ? 0 : (s >= N ? N - 1 : s);
    d = (d < 0) ? 0 : (d >= N ? N - 1 : d);
    uint idx = row_ptr[d] + atomicAdd(&cursor[d], 1u);
    srcid[idx] = make_int2(s, e);
}

__global__ void k_cvt(const float4* __restrict__ in, ushort4* __restrict__ outp, int n4) {
    int i = blockIdx.x * 256 + threadIdx.x;
    if (i >= n4) return;
    float4 v = in[i];
    ushort4 o;
    o.x = f2bf(v.x); o.y = f2bf(v.y); o.z = f2bf(v.z); o.w = f2bf(v.w);
    outp[i] = o;
}

// ---------------- g-projection pre-pack: Wgf[k][f] = sum_c Wq[k,c]*We[f,c] ----
__global__ void k_packg(const float* __restrict__ Wq, const float* __restrict__ bq,
                        const float* __restrict__ We, float* __restrict__ Wgf,
                        float* __restrict__ bgf, int C) {
    int id = blockIdx.x * 256 + threadIdx.x;
    if (id < 2048) {
        int k = id >> 4, f = id & 15;
        float s = 0.f;
        for (int c = 0; c < C; ++c) s = fmaf(Wq[k * C + c], We[f * C + c], s);
        Wgf[id] = s;              // layout [k*16+f]
    } else if (id < 2064) {
        int f = id - 2048;
        float s = 0.f;
        for (int c = 0; c < C; ++c) s = fmaf(bq[c], We[f * C + c], s);
        bgf[f] = s;
    }
}

// ---------- weight pack (cols: Wq|Wk|Wv|Ws|Wg -> 4C+16) + bias, merged -------
__global__ void k_packwb(const float* __restrict__ Wq, const float* __restrict__ bq,
                         const float* __restrict__ Wk, const float* __restrict__ bk,
                         const float* __restrict__ Wv, const float* __restrict__ bv,
                         const float* __restrict__ Ws, const float* __restrict__ bs,
                         const float* __restrict__ Wgf, const float* __restrict__ bgf,
                         ushort* __restrict__ Bp, float* __restrict__ biasc, int C) {
    int P = 4 * C + 16;
    int nct = P >> 4;
    int total = 4 * nct * 512;
    int id = blockIdx.x * 256 + threadIdx.x;
    if (id < total) {
        int j = id & 7;
        int rest = id >> 3;
        int lane = rest & 63;
        rest >>= 6;
        int ct = rest % nct;
        int kt = rest / nct;
        int k = kt * 32 + ((lane >> 4) << 3) + j;
        int c = (ct << 4) + (lane & 15);
        float w;
        if (c < 4 * C) {
            int mat = c / C, cc = c % C;
            const float* W = (mat == 0) ? Wq : (mat == 1) ? Wk : (mat == 2) ? Wv : Ws;
            w = W[k * C + cc];
        } else {
            w = Wgf[k * 16 + (c - 4 * C)];
        }
        Bp[id] = f2bf(w);
    } else if (id < total + P) {
        int c = id - total;
        float v;
        if (c < 4 * C) {
            int mat = c / C, cc = c % C;
            const float* b = (mat == 0) ? bq : (mat == 1) ? bk : (mat == 2) ? bv : bs;
            v = b[cc];
        } else {
            v = bgf[c - 4 * C];
        }
        biasc[c] = v;
    }
}

// ---------------- fused QKVSG GEMM (bf16 MFMA), 64-row x 256-col blocks ------
// A: [N,128] bf16. Cols [0,3C)->H (q|k|v), [3C,4C)->S (skip), [4C,4C+16)->g.
// Block = 4 waves (col-slices); each wave: 4 row-frags x 4 col-tiles.
__global__ __launch_bounds__(256) void k_gemm(const ushort* __restrict__ A,
                                              const ushort* __restrict__ Bp,
                                              const float* __restrict__ bias,
                                              ushort* __restrict__ H,
                                              ushort* __restrict__ S,
                                              ushort* __restrict__ g, int C, int N) {
    int fourC = 4 * C, threeC = 3 * C;
    int P = fourC + 16;
    int nct = P >> 4;
    int lane = threadIdx.x & 63;
    int wave = threadIdx.x >> 6;
    int quad = lane >> 4;
    int r = lane & 15;
    int m0 = blockIdx.y << 6;                       // 64 rows per block
    int ct0 = (blockIdx.x << 4) + (wave << 2);      // 4 col-tiles per wave
    if (ct0 >= nct) return;

    f32x4 acc[4][4];
#pragma unroll
    for (int rt = 0; rt < 4; ++rt)
#pragma unroll
        for (int i = 0; i < 4; ++i) acc[rt][i] = (f32x4){0.f, 0.f, 0.f, 0.f};

#pragma unroll
    for (int kk = 0; kk < 4; ++kk) {
        bf16x8 a[4];
#pragma unroll
        for (int rt = 0; rt < 4; ++rt) {
            int row = m0 + rt * 16 + r;
            if (row >= N) row = N - 1;              // pad rows: garbage, masked at store
            a[rt] = *(const bf16x8*)(A + (size_t)row * 128 + kk * 32 + (quad << 3));
        }
#pragma unroll
        for (int i = 0; i < 4; ++i) {
            if (ct0 + i < nct) {
                bf16x8 b = *(const bf16x8*)(Bp + ((size_t)((kk * nct + ct0 + i) << 6) + lane) * 8);
#pragma unroll
                for (int rt = 0; rt < 4; ++rt)
                    acc[rt][i] = __builtin_amdgcn_mfma_f32_16x16x32_bf16(a[rt], b, acc[rt][i], 0, 0, 0);
            }
        }
    }
#pragma unroll
    for (int i = 0; i < 4; ++i) {
        int cc = ((ct0 + i) << 4) + r;
        if (cc >= P) continue;
        float bi = bias[cc];
#pragma unroll
        for (int rt = 0; rt < 4; ++rt) {
#pragma unroll
            for (int reg = 0; reg < 4; ++reg) {
                int rr = m0 + rt * 16 + (quad << 2) + reg;
                if (rr >= N) continue;
                ushort val = f2bf(acc[rt][i][reg] + bi);
                if (cc < threeC)      H[(size_t)rr * threeC + cc] = val;
                else if (cc < fourC)  S[(size_t)rr * C + (cc - threeC)] = val;
                else                  g[(size_t)rr * 16 + (cc - fourC)] = val;
            }
        }
    }
}

// ---------------- edge attention: GSIZE-lane group per node, plain exp -------
// VERBATIM R6 (165us/494MB config). H: [N,3C] bf16 (q|k|v). S: skip on entry,
// output on exit. g: [N,16] bf16. Logits |alpha|<~2 by construction -> plain exp.
template <int C, int GSIZE, bool RELU>
__global__ __launch_bounds__(256, 6) void k_edge(const ushort* __restrict__ H,
                                                 ushort* __restrict__ S,
                                                 const ushort* __restrict__ g,
                                                 const uint* __restrict__ row_ptr,
                                                 const int2* __restrict__ srcid,
                                                 const float* __restrict__ eattr,
                                                 const float* __restrict__ We,
                                                 int N) {
    constexpr int VR = C / GSIZE;        // 8
    constexpr int TH = 3 * C;
    constexpr int GPB = 256 / GSIZE;     // groups per block
    __shared__ float swex[GPB][17];      // +1 pad: conflict-free group reads
    const float scale = (C == 128) ? 0.08838834764831843f : 0.0625f;  // 1/sqrt(C)
    const float foldk = 16.0f / (float)GSIZE;  // attr replication compensation

    int lane = threadIdx.x & (GSIZE - 1);
    int grp = threadIdx.x / GSIZE;
    int f = lane & 15;
    int node = blockIdx.x * GPB + grp;
    if (node >= N) return;

    float q[VR];
    {
        uint4 tt = *(const uint4*)(H + (size_t)node * TH + lane * VR);
        unpack8(tt, q);
    }
    float gl = bf2f(g[(size_t)node * 16 + f]);
    uint beg = row_ptr[node], end = row_ptr[node + 1];

    float l = 0.f, w = 0.f;
    float acc[VR];
#pragma unroll
    for (int j = 0; j < VR; ++j) acc[j] = 0.f;

    for (uint t = beg; t < end; t += 2) {
        bool has1 = (t + 1 < end);                 // group-uniform
        int2 se0 = srcid[t];
        int2 se1 = has1 ? srcid[t + 1] : se0;
        float at0 = eattr[(size_t)se0.y * 16 + f];
        float at1 = eattr[(size_t)se1.y * 16 + f];
        uint4 k0 = *(const uint4*)(H + (size_t)se0.x * TH + C + lane * VR);
        uint4 v0 = *(const uint4*)(H + (size_t)se0.x * TH + 2 * C + lane * VR);
        uint4 k1, v1;
        if (has1) {
            k1 = *(const uint4*)(H + (size_t)se1.x * TH + C + lane * VR);
            v1 = *(const uint4*)(H + (size_t)se1.x * TH + 2 * C + lane * VR);
        }
        float kf[VR];
        unpack8(k0, kf);
        float p0 = foldk * at0 * gl;               // attr.g folded into reduce
#pragma unroll
        for (int j = 0; j < VR; ++j) p0 = fmaf(q[j], kf[j], p0);
        float p1 = 0.f;
        if (has1) {
            unpack8(k1, kf);
            p1 = foldk * at1 * gl;
#pragma unroll
            for (int j = 0; j < VR; ++j) p1 = fmaf(q[j], kf[j], p1);
        }
        p0 += __shfl_xor(p0, 1); p1 += __shfl_xor(p1, 1);
        p0 += __shfl_xor(p0, 2); p1 += __shfl_xor(p1, 2);
        p0 += __shfl_xor(p0, 4); p1 += __shfl_xor(p1, 4);
        p0 += __shfl_xor(p0, 8); p1 += __shfl_xor(p1, 8);
        if (GSIZE == 32) { p0 += __shfl_xor(p0, 16); p1 += __shfl_xor(p1, 16); }
        float e0 = __expf(p0 * scale);
        float e1 = has1 ? __expf(p1 * scale) : 0.f;
        l += e0 + e1;
        w = fmaf(e0, at0, w);
        w = fmaf(e1, at1, w);
        float vf[VR];
        unpack8(v0, vf);
#pragma unroll
        for (int j = 0; j < VR; ++j) acc[j] = fmaf(e0, vf[j], acc[j]);
        if (has1) {
            unpack8(v1, vf);
#pragma unroll
            for (int j = 0; j < VR; ++j) acc[j] = fmaf(e1, vf[j], acc[j]);
        }
    }

    float inv = 1.f / (l + 1e-16f);   // empty node: acc=w=0 -> out = skip
    // exchange w_f (held on lane f; duplicated on lane 16+f when GSIZE=32)
    if (lane < 16) swex[grp][lane] = w;
    // same-wave LDS RAW: compiler inserts lgkmcnt wait; no barrier needed
    float ew[VR];
#pragma unroll
    for (int j = 0; j < VR; ++j) ew[j] = 0.f;
#pragma unroll
    for (int f2 = 0; f2 < 16; ++f2) {
        float wf = swex[grp][f2];
        const float* wrow = We + f2 * C + lane * VR;
#pragma unroll
        for (int u = 0; u < VR / 4; ++u) {
            float4 cv = *(const float4*)(wrow + u * 4);
            ew[u * 4 + 0] = fmaf(wf, cv.x, ew[u * 4 + 0]);
            ew[u * 4 + 1] = fmaf(wf, cv.y, ew[u * 4 + 1]);
            ew[u * 4 + 2] = fmaf(wf, cv.z, ew[u * 4 + 2]);
            ew[u * 4 + 3] = fmaf(wf, cv.w, ew[u * 4 + 3]);
        }
    }
    ushort* srow = S + (size_t)node * C + lane * VR;
    uint4 skv = *(const uint4*)srow;
    float sk[8];
    unpack8(skv, sk);
    uint4 ov;
    uint* op = (uint*)&ov;
#pragma unroll
    for (int h = 0; h < 4; ++h) {
        float o0 = (acc[2 * h] + ew[2 * h]) * inv + sk[2 * h];
        float o1 = (acc[2 * h + 1] + ew[2 * h + 1]) * inv + sk[2 * h + 1];
        if (RELU) { o0 = fmaxf(o0, 0.f); o1 = fmaxf(o1, 0.f); }
        op[h] = (uint)f2bf(o0) | ((uint)f2bf(o1) << 16);
    }
    *(uint4*)srow = ov;
}

// ---------------- classifier: out[N,10] = h3(bf16) @ Wc + bc ----------------
__global__ void k_cls(const ushort* __restrict__ h, const float* __restrict__ Wc,
                      const float* __restrict__ bc, float* __restrict__ outp, int N) {
    int t = blockIdx.x * 256 + threadIdx.x;
    int node = t >> 4;
    int c = t & 15;
    if (node >= N || c >= 10) return;
    const ushort* hr = h + (size_t)node * 256;
    float acc = 0.f;
#pragma unroll 4
    for (int k4 = 0; k4 < 64; ++k4) {
        uint2 u = *(const uint2*)(hr + k4 * 4);
        float h0 = bf2f((ushort)(u.x & 0xffffu));
        float h1 = bf2f((ushort)(u.x >> 16));
        float h2 = bf2f((ushort)(u.y & 0xffffu));
        float h3 = bf2f((ushort)(u.y >> 16));
        int kb = k4 * 4;
        acc = fmaf(h0, Wc[(kb + 0) * 10 + c], acc);
        acc = fmaf(h1, Wc[(kb + 1) * 10 + c], acc);
        acc = fmaf(h2, Wc[(kb + 2) * 10 + c], acc);
        acc = fmaf(h3, Wc[(kb + 3) * 10 + c], acc);
    }
    outp[node * 10 + c] = acc + bc[c];
}

// ---------------- launch ----------------
extern "C" void kernel_launch(void* const* d_in, const int* in_sizes, int n_in,
                              void* d_out, int out_size, void* d_ws, size_t ws_size,
                              hipStream_t stream) {
    const float* x = (const float*)d_in[0];
    const int* ei = (const int*)d_in[1];
    const float* eattr = (const float*)d_in[2];
    const int N = in_sizes[0] / 128;
    const int E = in_sizes[1] / 2;

    const float* Wq[3], *bq[3], *Wk[3], *bk[3], *Wv[3], *bv[3], *We[3], *Ws[3], *bs[3];
    for (int li = 0; li < 3; ++li) {
        int base = 3 + li * 9;
        Wq[li] = (const float*)d_in[base + 0];
        bq[li] = (const float*)d_in[base + 1];
        Wk[li] = (const float*)d_in[base + 2];
        bk[li] = (const float*)d_in[base + 3];
        Wv[li] = (const float*)d_in[base + 4];
        bv[li] = (const float*)d_in[base + 5];
        We[li] = (const float*)d_in[base + 6];
        Ws[li] = (const float*)d_in[base + 7];
        bs[li] = (const float*)d_in[base + 8];
    }
    const float* Wc = (const float*)d_in[30];
    const float* bc = (const float*)d_in[31];

    // workspace carve (~243 MB)
    size_t off = 0;
    char* base = (char*)d_ws;
    auto alloc = [&](size_t bytes) -> void* {
        void* p = base + off;
        off = (off + bytes + 255) & ~(size_t)255;
        return p;
    };
    ushort* SA = (ushort*)alloc((size_t)N * 256 * 2);   // skip/out ping
    ushort* SB = (ushort*)alloc((size_t)N * 128 * 2);   // pong (also xb)
    ushort* H  = (ushort*)alloc((size_t)N * 768 * 2);   // q|k|v (max 3C)
    ushort* gbuf = (ushort*)alloc((size_t)N * 16 * 2);  // g = We.q per node
    ushort* Bp = (ushort*)alloc(140000 * 2);            // packed weights
    float* biasc = (float*)alloc(1040 * 4);
    float* Wgf = (float*)alloc(2048 * 4);
    float* bgf = (float*)alloc(16 * 4);
    uint* row_ptr = (uint*)alloc((size_t)(N + 1) * 4);
    uint* counts = (uint*)alloc((size_t)N * 2 * 4);     // counts | cursor
    uint* cursor = counts + N;
    uint* bsum = (uint*)alloc(1024 * 4);
    int2* srcid = (int2*)alloc((size_t)E * 8);

    ushort* xb = SB;   // alias: xb dead after layer-1 GEMM

    int nb = (N + 1023) / 1024;

    // CSR build
    k_zero<<<(2 * N + 255) / 256, 256, 0, stream>>>(counts, 2 * N);
    k_hist<<<(E + 255) / 256, 256, 0, stream>>>(ei + E, counts, E, N);
    k_scan1<<<nb, 256, 0, stream>>>(counts, bsum, N);
    k_scan2<<<1, 64, 0, stream>>>(bsum, nb);
    k_scan3<<<nb, 256, 0, stream>>>(counts, bsum, row_ptr, N, E);
    k_fill<<<(E + 255) / 256, 256, 0, stream>>>(ei, row_ptr, cursor, srcid, E, N);

    // x -> bf16
    int n4 = N * 128 / 4;
    k_cvt<<<(n4 + 255) / 256, 256, 0, stream>>>((const float4*)x, (ushort4*)xb, n4);

    int gy = (N + 63) / 64;   // GEMM 64-row blocks

    for (int li = 0; li < 3; ++li) {
        int C = (li == 2) ? 256 : 128;
        int P = 4 * C + 16;
        int nct = P >> 4;
        int packTotal = 4 * nct * 512 + P;
        const ushort* A = (li == 0) ? xb : (li == 1) ? SA : SB;
        ushort* Sout = (li == 1) ? SB : SA;

        k_packg<<<9, 256, 0, stream>>>(Wq[li], bq[li], We[li], Wgf, bgf, C);
        k_packwb<<<(packTotal + 255) / 256, 256, 0, stream>>>(
            Wq[li], bq[li], Wk[li], bk[li], Wv[li], bv[li], Ws[li], bs[li],
            Wgf, bgf, Bp, biasc, C);
        k_gemm<<<dim3((nct + 15) / 16, gy), 256, 0, stream>>>(A, Bp, biasc, H, Sout, gbuf, C, N);
        if (li == 2)
            k_edge<256, 32, false><<<(N * 32 + 255) / 256, 256, 0, stream>>>(
                H, Sout, gbuf, row_ptr, srcid, eattr, We[li], N);
        else
            k_edge<128, 16, true><<<(N * 16 + 255) / 256, 256, 0, stream>>>(
                H, Sout, gbuf, row_ptr, srcid, eattr, We[li], N);
    }

    // classifier (layer-3 output is in SA)
    k_cls<<<(N * 16 + 255) / 256, 256, 0, stream>>>(SA, Wc, bc, (float*)d_out, N);
}